// Round 8
// baseline (452.664 us; speedup 1.0000x reference)
//
#include <hip/hip_runtime.h>
#include <stdint.h>

#define B_   8
#define D_   192      // Cin*3
#define N_   2048
#define KNb  11       // k+1

using u32 = uint32_t;
using u16 = unsigned short;
typedef _Float16 f16;
struct alignas(8) h4 { f16 x, y, z, w; };

typedef __attribute__((ext_vector_type(8)))  short short8;
typedef __attribute__((ext_vector_type(16))) float f32x16;

__device__ __forceinline__ float bf2f(u16 h){ union{u32 i; float f;} x; x.i = ((u32)h) << 16; return x.f; }
__device__ __forceinline__ u16 f2bf(float f){
  union{float f; u32 i;} x; x.f = f;
  u32 r = (x.i + 0x7fffu + ((x.i >> 16) & 1u)) >> 16;
  return (u16)r;
}

// ---------------- K0: bf16 hi/lo split + fp32 transpose + f64 xx ----------------
__global__ __launch_bounds__(256) void split_kernel(const float* __restrict__ x,
                                                    short* __restrict__ Xs,
                                                    float* __restrict__ xT,
                                                    double* __restrict__ xxd){
  __shared__ float A[D_ * 64];                       // 48 KB, [d][m]
  const int b = blockIdx.y, m0 = blockIdx.x * 64, t = threadIdx.x;
  const size_t xb = (size_t)b * D_ * N_;
  #pragma unroll
  for (int q = 0; q < 48; ++q){
    int p = t + 256*q;
    int d = p >> 6, i = p & 63;
    A[d*64 + i] = x[xb + (size_t)d*N_ + m0 + i];
  }
  __syncthreads();
  const int m = t & 63, seg = t >> 6;                // 4 segs of 48 d's per point
  short* orow = Xs + ((size_t)b*N_ + m0 + m) * 384;
  #pragma unroll
  for (int c8 = 0; c8 < 6; ++c8){
    union { u16 s[8]; int4 v; } uh, ul;
    #pragma unroll
    for (int j = 0; j < 8; ++j){
      int d = seg*48 + c8*8 + j;
      float v = A[d*64 + m];
      u16 h = f2bf(v);
      uh.s[j] = h;
      ul.s[j] = f2bf(v - bf2f(h));
    }
    *(int4*)(orow + seg*48 + c8*8)       = uh.v;
    *(int4*)(orow + 192 + seg*48 + c8*8) = ul.v;
  }
  {
    float* trow = xT + ((size_t)b*N_ + m0 + m) * 192 + seg*48;
    #pragma unroll
    for (int j = 0; j < 12; ++j){
      float4 v = { A[(seg*48 + 4*j + 0)*64 + m], A[(seg*48 + 4*j + 1)*64 + m],
                   A[(seg*48 + 4*j + 2)*64 + m], A[(seg*48 + 4*j + 3)*64 + m] };
      *(float4*)(trow + 4*j) = v;
    }
  }
  if (t < 64){
    double s = 0.0;
    #pragma unroll 4
    for (int d = 0; d < D_; ++d){ double v = (double)A[d*64 + t]; s = fma(v, v, s); }
    xxd[b*N_ + m0 + t] = s;
  }
}

// ---------------- K1: MFMA kNN v2 ----------------
// grid (8 b, 64 stripes of 32 n): linear%8 = b -> XCD-local Xs slice.
// A-frags: direct global->reg (prefetched 1 kc ahead), never LDS.
// B: LDS dbuf, swizzle o = g*128 + r*4 + (ch ^ ((mr>>1)&3)) -- conflict-free R+W.
// CT/MV alias B buffers. LDS 34,048 B; VGPR capped 128 (launch_bounds 512,4).
#define KB0  0
#define KB1  16384
#define KXXS 32896
#define KXXN 33920
#define KSZ  34048
__global__ __launch_bounds__(512, 4) void knn_kernel(const short* __restrict__ Xs,
                                                     const double* __restrict__ xxd,
                                                     u16* __restrict__ cand){
  __shared__ __align__(16) char smem[KSZ];
  float* CT  = (float*)(smem);
  float* XXS = (float*)(smem + KXXS);
  float* XXN = (float*)(smem + KXXN);

  const int b = blockIdx.x, n0 = blockIdx.y * 32;
  const int t = threadIdx.x, lane = t & 63, w = t >> 6;
  const int l31 = lane & 31, lh = lane >> 5;
  const short* xsb = Xs + (size_t)b * N_ * 384;

  // A-fragment global base: row n0+l31, 8-short half lh; chunk j at +j*16 shorts
  const short* abase = xsb + (size_t)(n0 + l31)*384 + lh*8;

  // B staging thread->chunk map (coalesced source), swizzled LDS index
  const int mrA = t >> 2, mrB = (t + 512) >> 2, chA = t & 3;
  const int oA = (mrA>>5)*128 + (mrA&31)*4 + (chA ^ ((mrA>>1)&3));
  const int oB = (mrB>>5)*128 + (mrB&31)*4 + (chA ^ ((mrB>>1)&3));
  // B fragment read index (row w*32+l31, chunk 2ks+lh)
  const int rmask = (l31 >> 1) & 3;
  const int rb0 = w*128 + l31*4;

  if (t < 32) XXN[t] = (float)xxd[b*N_ + n0 + t];

  float bv[10]; int bi[10];
  #pragma unroll
  for (int j = 0; j < 10; ++j){ bv[j] = -3.4e38f; bi[j] = 0; }

  short8 a0 = *(const short8*)(abase);         // kc=0, ks=0
  short8 a1 = *(const short8*)(abase + 16);    // kc=0, ks=1

  for (int st = 0; st < 8; ++st){
    const int m0 = st * 256;
    if (t < 256) XXS[t] = (float)xxd[b*N_ + m0 + t];
    {   // stage B kc=0
      short8 v0 = *(const short8*)(xsb + (size_t)(m0 + mrA)*384 + chA*8);
      short8 v1 = *(const short8*)(xsb + (size_t)(m0 + mrB)*384 + chA*8);
      *(short8*)(smem + KB0 + oA*16) = v0;
      *(short8*)(smem + KB0 + oB*16) = v1;
    }
    __syncthreads();

    f32x16 acc = (f32x16)0.0f;
    #pragma unroll
    for (int kc = 0; kc < 12; ++kc){
      const char* cur = smem + ((kc & 1) ? KB1 : KB0);
      short8 p0, p1;
      if (kc < 11){
        p0 = *(const short8*)(xsb + (size_t)(m0 + mrA)*384 + (kc+1)*32 + chA*8);
        p1 = *(const short8*)(xsb + (size_t)(m0 + mrB)*384 + (kc+1)*32 + chA*8);
      }
      const int jn = (kc < 11) ? (kc+1)*2 : 0;     // af prefetch (wraps to kc0 for next st)
      short8 an0 = *(const short8*)(abase + jn*16);
      short8 an1 = *(const short8*)(abase + jn*16 + 16);

      short8 bf0 = *(const short8*)(cur + (rb0 + ((lh    ) ^ rmask))*16);
      acc = __builtin_amdgcn_mfma_f32_32x32x16_bf16(a0, bf0, acc, 0, 0, 0);
      short8 bf1 = *(const short8*)(cur + (rb0 + ((lh + 2) ^ rmask))*16);
      acc = __builtin_amdgcn_mfma_f32_32x32x16_bf16(a1, bf1, acc, 0, 0, 0);

      if (kc < 11){
        char* nb = smem + (((kc+1) & 1) ? KB1 : KB0);
        *(short8*)(nb + oA*16) = p0;
        *(short8*)(nb + oB*16) = p1;
      }
      __syncthreads();
      a0 = an0; a1 = an1;
    }

    // scatter acc -> CT[n][m], stride 257 (conflict-free); aliases dead B buffers
    #pragma unroll
    for (int reg = 0; reg < 16; ++reg){
      int r = (reg & 3) + 8*(reg >> 2) + 4*lh;
      CT[r*257 + w*32 + l31] = acc[reg];
    }
    __syncthreads();

    {   // scan: thread (r = t&31, sub = t>>5) covers 16 m-cols
      const int r = t & 31, sub = t >> 5;
      const float xn = XXN[r];
      const float* ct = CT + r*257 + sub*16;
      const float* xs = XXS + sub*16;
      #pragma unroll
      for (int i = 0; i < 16; ++i){
        float v = 2.f*ct[i] - xs[i] - xn;
        int m = m0 + sub*16 + i;
        if (v > bv[0]){
          bv[0] = v; bi[0] = m;
          #pragma unroll
          for (int s = 0; s < 9; ++s){
            if (bv[s] > bv[s+1]){
              float tv = bv[s]; bv[s] = bv[s+1]; bv[s+1] = tv;
              int   ti = bi[s]; bi[s] = bi[s+1]; bi[s+1] = ti;
            }
          }
        }
      }
    }
    __syncthreads();
  }

  // merge 16 lists x 10 per row -> top-16 window (list rows = sub*32+r: bank-spread)
  float* MV = (float*)smem;                        // 512*10*4 = 20,480
  u16*   MI = (u16*)(smem + 20480);                // 10,240
  {
    const int r = t & 31, sub = t >> 5;
    #pragma unroll
    for (int j = 0; j < 10; ++j){
      MV[(sub*32 + r)*10 + j] = bv[j];
      MI[(sub*32 + r)*10 + j] = (u16)bi[j];
    }
  }
  __syncthreads();
  if (t < 32){
    int head[16];
    #pragma unroll
    for (int q = 0; q < 16; ++q) head[q] = 9;
    const size_t ob = ((size_t)b*N_ + n0 + t) * 16;
    for (int s = 0; s < 16; ++s){
      float bvv = -3.4e38f; int bm = 0x7fffffff, bq = 0;
      #pragma unroll
      for (int q = 0; q < 16; ++q){
        int hh = head[q];
        if (hh >= 0){
          float v = MV[(q*32 + t)*10 + hh];
          int   m = (int)MI[(q*32 + t)*10 + hh];
          if ((v > bvv) || ((v == bvv) && (m < bm))){ bvv = v; bm = m; bq = q; }
        }
      }
      cand[ob + s] = (u16)(bm & 2047);
      #pragma unroll
      for (int q = 0; q < 16; ++q) head[q] -= (q == bq) ? 1 : 0;
    }
  }
}

// ---------------- K1b: f64 refine, register-only, shuffle-rank top-11 ----------------
__global__ __launch_bounds__(256) void refine_kernel(const float* __restrict__ xT,
                                                     const u16* __restrict__ cand,
                                                     const double* __restrict__ xxd,
                                                     int* __restrict__ idxout){
  const int wv = threadIdx.x >> 6, ln = threadIdx.x & 63;
  const int g = blockIdx.x * 4 + wv;               // 0..16383
  const int b = g >> 11, n = g & 2047;
  const int c = ln >> 2, part = ln & 3;
  const int m = (int)cand[(size_t)g*16 + c] & 2047;
  const float4* pn = (const float4*)(xT + ((size_t)b*N_ + n)*192 + part*48);
  const float4* pm = (const float4*)(xT + ((size_t)b*N_ + m)*192 + part*48);
  double s = 0.0;
  #pragma unroll
  for (int j = 0; j < 12; ++j){
    float4 a = pn[j], bb = pm[j];
    s = fma((double)a.x, (double)bb.x, s);
    s = fma((double)a.y, (double)bb.y, s);
    s = fma((double)a.z, (double)bb.z, s);
    s = fma((double)a.w, (double)bb.w, s);
  }
  s += __shfl_down(s, 2, 64);
  s += __shfl_down(s, 1, 64);                      // part==0 lanes hold full dot
  double v = 2.0*s - xxd[b*N_ + n] - xxd[b*N_ + m];
  int rank = 0;
  #pragma unroll
  for (int q = 0; q < 16; ++q){
    double vq = __shfl(v, q*4, 64);
    int    mq = __shfl(m, q*4, 64);
    bool beat = (vq > v) || ((vq == v) && (mq < m));
    rank += beat ? 1 : 0;
  }
  if (part == 0 && rank < KNb)
    idxout[(size_t)g*KNb + rank] = m;
}

// ---------------- K2: P0/D0 from xT (coalesced + broadcast LDS) ----------------
__global__ __launch_bounds__(256, 2) void project_kernel(const float* __restrict__ xT,
                                                         const float* __restrict__ Wf,
                                                         const float* __restrict__ Wd,
                                                         h4* __restrict__ P0h,
                                                         h4* __restrict__ D0h){
  __shared__ float A[64 * 192];                    // 48 KB, [m][e]
  const int b = blockIdx.x, m0 = blockIdx.y * 64, t = threadIdx.x;
  const int c = t & 63, mg = t >> 6;

  float wf[64], wd[64];
  #pragma unroll
  for (int q = 0; q < 16; ++q){
    float4 uf = *(const float4*)(Wf + c*64 + q*4);
    wf[q*4+0]=uf.x; wf[q*4+1]=uf.y; wf[q*4+2]=uf.z; wf[q*4+3]=uf.w;
    float4 ud = *(const float4*)(Wd + c*64 + q*4);
    wd[q*4+0]=ud.x; wd[q*4+1]=ud.y; wd[q*4+2]=ud.z; wd[q*4+3]=ud.w;
  }
  {
    const float4* src = (const float4*)(xT + ((size_t)b*N_ + m0)*192);
    float4* dst = (float4*)A;
    #pragma unroll
    for (int j = 0; j < 12; ++j) dst[t + 256*j] = src[t + 256*j];
  }
  __syncthreads();

  for (int mi = 0; mi < 16; ++mi){
    int m = mg*16 + mi;
    const float4* row = (const float4*)(A + m*192);
    float p[3] = {0.f,0.f,0.f}, qv[3] = {0.f,0.f,0.f};
    #pragma unroll
    for (int v4 = 0; v4 < 48; ++v4){
      float4 f = row[v4];
      const int e = v4*4;
      p [(e+0)%3] = fmaf(wf[(e+0)/3], f.x, p [(e+0)%3]);
      qv[(e+0)%3] = fmaf(wd[(e+0)/3], f.x, qv[(e+0)%3]);
      p [(e+1)%3] = fmaf(wf[(e+1)/3], f.y, p [(e+1)%3]);
      qv[(e+1)%3] = fmaf(wd[(e+1)/3], f.y, qv[(e+1)%3]);
      p [(e+2)%3] = fmaf(wf[(e+2)/3], f.z, p [(e+2)%3]);
      qv[(e+2)%3] = fmaf(wd[(e+2)/3], f.z, qv[(e+2)%3]);
      p [(e+3)%3] = fmaf(wf[(e+3)/3], f.w, p [(e+3)%3]);
      qv[(e+3)%3] = fmaf(wd[(e+3)/3], f.w, qv[(e+3)%3]);
    }
    float nrm = sqrtf(p[0]*p[0] + p[1]*p[1] + p[2]*p[2]);
    float dsq = qv[0]*qv[0] + qv[1]*qv[1] + qv[2]*qv[2];
    size_t base = ((size_t)b*N_ + m0 + m)*64 + c;
    h4 vp; vp.x = (f16)p[0];  vp.y = (f16)p[1];  vp.z = (f16)p[2];  vp.w = (f16)nrm;
    h4 vd; vd.x = (f16)qv[0]; vd.y = (f16)qv[1]; vd.z = (f16)qv[2]; vd.w = (f16)dsq;
    P0h[base] = vp;
    D0h[base] = vd;
  }
}

// ---------------- K3a: neighbor occurrence counts ----------------
__global__ __launch_bounds__(256) void count_kernel(const int* __restrict__ idxin, int* __restrict__ cnt){
  int i = blockIdx.x*256 + threadIdx.x;
  if (i < B_*N_*KNb){
    int b = i / (N_*KNb);
    atomicAdd(&cnt[b*N_ + (idxin[i] & 2047)], 1);
  }
}

// ---------------- K3b: per-channel weighted sum / sumsq of norms ----------------
__global__ __launch_bounds__(256) void stats_kernel(const h4* __restrict__ P0h,
                                                    const int* __restrict__ cnt,
                                                    float* __restrict__ gs){
  const int b = blockIdx.x >> 3;
  const int chunk = blockIdx.x & 7;
  const int w = threadIdx.x >> 6, c = threadIdx.x & 63;
  float s = 0.f, s2 = 0.f;
  const int mbase = chunk*256 + w*64;
  for (int i = 0; i < 64; ++i){
    int m = mbase + i;
    float wt = (float)cnt[b*N_ + m];
    float nv = (float)P0h[((size_t)b*N_ + m)*64 + c].w;
    s  = fmaf(wt, nv, s);
    s2 = fmaf(wt*nv, nv, s2);
  }
  __shared__ float red[8][64];
  red[w][c] = s; red[4+w][c] = s2;
  __syncthreads();
  if (w == 0) atomicAdd(&gs[c],    red[0][c]+red[1][c]+red[2][c]+red[3][c]);
  if (w == 1) atomicAdd(&gs[64+c], red[4][c]+red[5][c]+red[6][c]+red[7][c]);
}

// ---------------- K4: gather + BN + nonlinearity + mean over K ----------------
__global__ __launch_bounds__(512) void out_kernel(const h4* __restrict__ P0h, const h4* __restrict__ D0h,
                                                  const int* __restrict__ idxin, const float* __restrict__ gs,
                                                  const float* __restrict__ gamma, const float* __restrict__ beta,
                                                  float* __restrict__ outp){
  __shared__ float res[64 * 193];                  // 49,408 B
  const int b  = blockIdx.x;
  const int n0 = blockIdx.y * 64;
  const int t = threadIdx.x, w = t >> 6, c = t & 63;
  const float Ninv = 1.f / (float)(B_*N_*KNb);
  float mean = gs[c] * Ninv;
  float var  = gs[64+c] * Ninv - mean*mean;
  float istd = rsqrtf(var + 1e-5f);
  float sa = istd * gamma[c];
  float be = beta[c];
  const float kinv = 1.f/11.f;
  for (int i = 0; i < 8; ++i){
    int n = n0 + w*8 + i;
    const int* ip = idxin + ((size_t)b*N_ + n)*KNb;
    float a0=0, a1=0, a2=0;
    #pragma unroll
    for (int k = 0; k < KNb; ++k){
      int m = ip[k] & 2047;
      size_t base = ((size_t)b*N_ + m)*64 + c;
      h4 P  = P0h[base];
      h4 Dv = D0h[base];
      float pw = (float)P.w;
      float nb = (pw - mean)*sa + be;
      float sc = nb / pw;
      float p0 = (float)P.x*sc, p1 = (float)P.y*sc, p2 = (float)P.z*sc;
      float d0 = (float)Dv.x, d1 = (float)Dv.y, d2 = (float)Dv.z;
      float dot = p0*d0 + p1*d1 + p2*d2;
      float f = (dot >= 0.f) ? 0.f : dot / ((float)Dv.w + 1e-6f);
      a0 += p0 - f*d0; a1 += p1 - f*d1; a2 += p2 - f*d2;
    }
    int row = w*8 + i;
    res[row*193 + 3*c + 0] = a0*kinv;
    res[row*193 + 3*c + 1] = a1*kinv;
    res[row*193 + 3*c + 2] = a2*kinv;
  }
  __syncthreads();
  #pragma unroll
  for (int j = 0; j < 6; ++j){
    int p = t + 512*j;
    int cdim = p >> 4, nq = p & 15;
    float4 v = { res[(nq*4 + 0)*193 + cdim], res[(nq*4 + 1)*193 + cdim],
                 res[(nq*4 + 2)*193 + cdim], res[(nq*4 + 3)*193 + cdim] };
    *(float4*)(outp + ((size_t)b*192 + cdim)*N_ + n0 + nq*4) = v;
  }
}

extern "C" void kernel_launch(void* const* d_in, const int* in_sizes, int n_in,
                              void* d_out, int out_size, void* d_ws, size_t ws_size,
                              hipStream_t stream){
  const float* x     = (const float*)d_in[0];
  const float* Wf    = (const float*)d_in[1];
  const float* Wd    = (const float*)d_in[2];
  const float* gamma = (const float*)d_in[3];
  const float* beta  = (const float*)d_in[4];
  float* outp = (float*)d_out;

  // ws >= 30,408,704 B proven in R6 (refine_fast ran).
  char* ws = (char*)d_ws;
  int*    idx  = (int*)   (ws);                 // 720,896
  int*    cnt  = (int*)   (ws + 720896);        // 65,536
  float*  gs   = (float*) (ws + 786432);        // 512
  h4*     P0h  = (h4*)    (ws + 1048576);       // 8,388,608
  h4*     D0h  = (h4*)    (ws + 9437184);       // 8,388,608 (ends 17,825,792)
  short*  Xs   = (short*) (ws + 1048576);       //   alias, consumed pre-project
  double* xxd  = (double*)(ws + 13631488);      //   alias (lives in D0h region pre-project)
  u16*    cand = (u16*)   (ws + 13762560);      //   alias
  float*  xT   = (float*) (ws + 17825792);      // 12,582,912 (ends 30,408,704)

  hipMemsetAsync(cnt, 0, 66048, stream);        // zero cnt + gs (contiguous)
  split_kernel  <<<dim3(32, 8),  256, 0, stream>>>(x, Xs, xT, xxd);
  knn_kernel    <<<dim3(8, 64),  512, 0, stream>>>(Xs, xxd, cand);
  refine_kernel <<<4096,         256, 0, stream>>>(xT, cand, xxd, idx);
  project_kernel<<<dim3(8, 32),  256, 0, stream>>>(xT, Wf, Wd, P0h, D0h);
  count_kernel  <<<704,          256, 0, stream>>>(idx, cnt);
  stats_kernel  <<<64,           256, 0, stream>>>(P0h, cnt, gs);
  out_kernel    <<<dim3(8, 32),  512, 0, stream>>>(P0h, D0h, idx, gs, gamma, beta, outp);
}

// Round 9
// 387.922 us; speedup vs baseline: 1.1669x; 1.1669x over previous
//
#include <hip/hip_runtime.h>
#include <stdint.h>

#define B_   8
#define D_   192      // Cin*3
#define N_   2048
#define KNb  11       // k+1

using u32 = uint32_t;
using u16 = unsigned short;
typedef _Float16 f16;
struct alignas(8) h4 { f16 x, y, z, w; };

typedef __attribute__((ext_vector_type(8)))  short short8;
typedef __attribute__((ext_vector_type(16))) float f32x16;

__device__ __forceinline__ float bf2f(u16 h){ union{u32 i; float f;} x; x.i = ((u32)h) << 16; return x.f; }
__device__ __forceinline__ u16 f2bf(float f){
  union{float f; u32 i;} x; x.f = f;
  u32 r = (x.i + 0x7fffu + ((x.i >> 16) & 1u)) >> 16;
  return (u16)r;
}

// ---------------- K0: bf16 hi/lo split + fp32 transpose + f64 xx ----------------
__global__ __launch_bounds__(256) void split_kernel(const float* __restrict__ x,
                                                    short* __restrict__ Xs,
                                                    float* __restrict__ xT,
                                                    double* __restrict__ xxd){
  __shared__ float A[D_ * 64];                       // 48 KB, [d][m]
  const int b = blockIdx.y, m0 = blockIdx.x * 64, t = threadIdx.x;
  const size_t xb = (size_t)b * D_ * N_;
  #pragma unroll
  for (int q = 0; q < 48; ++q){
    int p = t + 256*q;
    int d = p >> 6, i = p & 63;
    A[d*64 + i] = x[xb + (size_t)d*N_ + m0 + i];
  }
  __syncthreads();
  const int m = t & 63, seg = t >> 6;                // 4 segs of 48 d's per point
  short* orow = Xs + ((size_t)b*N_ + m0 + m) * 384;
  #pragma unroll
  for (int c8 = 0; c8 < 6; ++c8){
    union { u16 s[8]; int4 v; } uh, ul;
    #pragma unroll
    for (int j = 0; j < 8; ++j){
      int d = seg*48 + c8*8 + j;
      float v = A[d*64 + m];
      u16 h = f2bf(v);
      uh.s[j] = h;
      ul.s[j] = f2bf(v - bf2f(h));
    }
    *(int4*)(orow + seg*48 + c8*8)       = uh.v;
    *(int4*)(orow + 192 + seg*48 + c8*8) = ul.v;
  }
  {
    float* trow = xT + ((size_t)b*N_ + m0 + m) * 192 + seg*48;
    #pragma unroll
    for (int j = 0; j < 12; ++j){
      float4 v = { A[(seg*48 + 4*j + 0)*64 + m], A[(seg*48 + 4*j + 1)*64 + m],
                   A[(seg*48 + 4*j + 2)*64 + m], A[(seg*48 + 4*j + 3)*64 + m] };
      *(float4*)(trow + 4*j) = v;
    }
  }
  if (t < 64){
    double s = 0.0;
    #pragma unroll 4
    for (int d = 0; d < D_; ++d){ double v = (double)A[d*64 + t]; s = fma(v, v, s); }
    xxd[b*N_ + m0 + t] = s;
  }
}

// ---------------- K1: MFMA kNN v3 = R7 A-in-LDS + R8 conflict-free B swizzle ----------------
// grid (8 b, 64 stripes of 32 n): linear%8 = b -> XCD-local Xs slice.
// LDS: A 24,576 | B dbuf 2x16,384 (CT 32,896 aliases B) | XXS 1,024 | XXN 128 = 58,624
#define KLA   0
#define KLB0  24576
#define KLB1  40960
#define KLCT  24576    // alias over B0+B1 (+128B spill into pad)
#define KXXS  57472
#define KXXN  58496
#define KSZ   58624
__global__ __launch_bounds__(512, 4) void knn_kernel(const short* __restrict__ Xs,
                                                     const double* __restrict__ xxd,
                                                     u16* __restrict__ cand){
  __shared__ __align__(16) char smem[KSZ];
  float* CT  = (float*)(smem + KLCT);
  float* XXS = (float*)(smem + KXXS);
  float* XXN = (float*)(smem + KXXN);

  const int b = blockIdx.x, n0 = blockIdx.y * 32;
  const int t = threadIdx.x, lane = t & 63, w = t >> 6;
  const int l31 = lane & 31, lh = lane >> 5;
  const short* xsb = Xs + (size_t)b * N_ * 384;

  // stage A-frags once: [ks 0..23][ln = half*32 + row][16B]  (write + read conflict-free)
  #pragma unroll
  for (int j = 0; j < 3; ++j){
    int p = t + 512*j;                 // 0..1535
    int ks = p >> 6, ln = p & 63;
    int am = ln & 31, half = ln >> 5;
    int4 v = *(const int4*)(xsb + (size_t)(n0 + am)*384 + ks*16 + half*8);
    *(int4*)(smem + KLA + ks*1024 + ln*16) = v;
  }
  if (t < 32) XXN[t] = (float)xxd[b*N_ + n0 + t];

  // B staging map: thread t covers rows mrA/mrB, chunk-quarter chA; swizzled dest
  const int mrA = t >> 2, mrB = (t + 512) >> 2, chA = t & 3;
  const int oA = (mrA>>5)*128 + (mrA&31)*4 + (chA ^ ((mrA>>1)&3));
  const int oB = (mrB>>5)*128 + (mrB&31)*4 + (chA ^ ((mrB>>1)&3));
  // B fragment read: row w*32+l31, chunk lh / lh+2
  const int rmask = (l31 >> 1) & 3;
  const int rb0 = w*128 + l31*4;

  float bv[10]; int bi[10];
  #pragma unroll
  for (int j = 0; j < 10; ++j){ bv[j] = -3.4e38f; bi[j] = 0; }

  for (int st = 0; st < 8; ++st){
    const int m0 = st * 256;
    if (t < 256) XXS[t] = (float)xxd[b*N_ + m0 + t];
    {   // stage B kc=0
      short8 v0 = *(const short8*)(xsb + (size_t)(m0 + mrA)*384 + chA*8);
      short8 v1 = *(const short8*)(xsb + (size_t)(m0 + mrB)*384 + chA*8);
      *(short8*)(smem + KLB0 + oA*16) = v0;
      *(short8*)(smem + KLB0 + oB*16) = v1;
    }
    __syncthreads();

    f32x16 acc = (f32x16)0.0f;
    #pragma unroll 4
    for (int kc = 0; kc < 12; ++kc){
      const char* cur = smem + ((kc & 1) ? KLB1 : KLB0);
      short8 p0, p1;
      if (kc < 11){
        p0 = *(const short8*)(xsb + (size_t)(m0 + mrA)*384 + (kc+1)*32 + chA*8);
        p1 = *(const short8*)(xsb + (size_t)(m0 + mrB)*384 + (kc+1)*32 + chA*8);
      }
      #pragma unroll
      for (int ks = 0; ks < 2; ++ks){
        short8 af = *(const short8*)(smem + KLA + (kc*2 + ks)*1024 + lane*16);
        short8 bf = *(const short8*)(cur + (rb0 + ((lh + 2*ks) ^ rmask))*16);
        acc = __builtin_amdgcn_mfma_f32_32x32x16_bf16(af, bf, acc, 0, 0, 0);
      }
      if (kc < 11){
        char* nb = smem + (((kc+1) & 1) ? KLB1 : KLB0);
        *(short8*)(nb + oA*16) = p0;
        *(short8*)(nb + oB*16) = p1;
      }
      __syncthreads();
    }

    // scatter acc -> CT[n][m], stride 257 (conflict-free); aliases dead B buffers
    #pragma unroll
    for (int reg = 0; reg < 16; ++reg){
      int r = (reg & 3) + 8*(reg >> 2) + 4*lh;
      CT[r*257 + w*32 + l31] = acc[reg];
    }
    __syncthreads();

    {   // scan: thread (r = t&31, sub = t>>5) covers 16 m-cols
      const int r = t & 31, sub = t >> 5;
      const float xn = XXN[r];
      const float* ct = CT + r*257 + sub*16;
      const float* xs = XXS + sub*16;
      #pragma unroll
      for (int i = 0; i < 16; ++i){
        float v = 2.f*ct[i] - xs[i] - xn;
        int m = m0 + sub*16 + i;
        if (v > bv[0]){
          bv[0] = v; bi[0] = m;
          #pragma unroll
          for (int s = 0; s < 9; ++s){
            if (bv[s] > bv[s+1]){
              float tv = bv[s]; bv[s] = bv[s+1]; bv[s+1] = tv;
              int   ti = bi[s]; bi[s] = bi[s+1]; bi[s+1] = ti;
            }
          }
        }
      }
    }
    __syncthreads();
  }

  // merge 16 lists x 10 per row -> top-16 window (bank-spread rows)
  float* MV = (float*)smem;                        // 512*10*4 = 20,480
  u16*   MI = (u16*)(smem + 20480);                // 10,240
  __syncthreads();
  {
    const int r = t & 31, sub = t >> 5;
    #pragma unroll
    for (int j = 0; j < 10; ++j){
      MV[(sub*32 + r)*10 + j] = bv[j];
      MI[(sub*32 + r)*10 + j] = (u16)bi[j];
    }
  }
  __syncthreads();
  if (t < 32){
    int head[16];
    #pragma unroll
    for (int q = 0; q < 16; ++q) head[q] = 9;
    const size_t ob = ((size_t)b*N_ + n0 + t) * 16;
    for (int s = 0; s < 16; ++s){
      float bvv = -3.4e38f; int bm = 0x7fffffff, bq = 0;
      #pragma unroll
      for (int q = 0; q < 16; ++q){
        int hh = head[q];
        if (hh >= 0){
          float v = MV[(q*32 + t)*10 + hh];
          int   m = (int)MI[(q*32 + t)*10 + hh];
          if ((v > bvv) || ((v == bvv) && (m < bm))){ bvv = v; bm = m; bq = q; }
        }
      }
      cand[ob + s] = (u16)(bm & 2047);
      #pragma unroll
      for (int q = 0; q < 16; ++q) head[q] -= (q == bq) ? 1 : 0;
    }
  }
}

// ---------------- K1b: f64 refine, register-only, shuffle-rank top-11 ----------------
__global__ __launch_bounds__(256) void refine_kernel(const float* __restrict__ xT,
                                                     const u16* __restrict__ cand,
                                                     const double* __restrict__ xxd,
                                                     int* __restrict__ idxout){
  const int wv = threadIdx.x >> 6, ln = threadIdx.x & 63;
  const int g = blockIdx.x * 4 + wv;               // 0..16383
  const int b = g >> 11, n = g & 2047;
  const int c = ln >> 2, part = ln & 3;
  const int m = (int)cand[(size_t)g*16 + c] & 2047;
  const float4* pn = (const float4*)(xT + ((size_t)b*N_ + n)*192 + part*48);
  const float4* pm = (const float4*)(xT + ((size_t)b*N_ + m)*192 + part*48);
  double s = 0.0;
  #pragma unroll
  for (int j = 0; j < 12; ++j){
    float4 a = pn[j], bb = pm[j];
    s = fma((double)a.x, (double)bb.x, s);
    s = fma((double)a.y, (double)bb.y, s);
    s = fma((double)a.z, (double)bb.z, s);
    s = fma((double)a.w, (double)bb.w, s);
  }
  s += __shfl_down(s, 2, 64);
  s += __shfl_down(s, 1, 64);                      // part==0 lanes hold full dot
  double v = 2.0*s - xxd[b*N_ + n] - xxd[b*N_ + m];
  int rank = 0;
  #pragma unroll
  for (int q = 0; q < 16; ++q){
    double vq = __shfl(v, q*4, 64);
    int    mq = __shfl(m, q*4, 64);
    bool beat = (vq > v) || ((vq == v) && (mq < m));
    rank += beat ? 1 : 0;
  }
  if (part == 0 && rank < KNb)
    idxout[(size_t)g*KNb + rank] = m;
}

// ---------------- K2: P0/D0 from xT (coalesced + broadcast LDS) ----------------
__global__ __launch_bounds__(256, 2) void project_kernel(const float* __restrict__ xT,
                                                         const float* __restrict__ Wf,
                                                         const float* __restrict__ Wd,
                                                         h4* __restrict__ P0h,
                                                         h4* __restrict__ D0h){
  __shared__ float A[64 * 192];                    // 48 KB, [m][e]
  const int b = blockIdx.x, m0 = blockIdx.y * 64, t = threadIdx.x;
  const int c = t & 63, mg = t >> 6;

  float wf[64], wd[64];
  #pragma unroll
  for (int q = 0; q < 16; ++q){
    float4 uf = *(const float4*)(Wf + c*64 + q*4);
    wf[q*4+0]=uf.x; wf[q*4+1]=uf.y; wf[q*4+2]=uf.z; wf[q*4+3]=uf.w;
    float4 ud = *(const float4*)(Wd + c*64 + q*4);
    wd[q*4+0]=ud.x; wd[q*4+1]=ud.y; wd[q*4+2]=ud.z; wd[q*4+3]=ud.w;
  }
  {
    const float4* src = (const float4*)(xT + ((size_t)b*N_ + m0)*192);
    float4* dst = (float4*)A;
    #pragma unroll
    for (int j = 0; j < 12; ++j) dst[t + 256*j] = src[t + 256*j];
  }
  __syncthreads();

  for (int mi = 0; mi < 16; ++mi){
    int m = mg*16 + mi;
    const float4* row = (const float4*)(A + m*192);
    float p[3] = {0.f,0.f,0.f}, qv[3] = {0.f,0.f,0.f};
    #pragma unroll
    for (int v4 = 0; v4 < 48; ++v4){
      float4 f = row[v4];
      const int e = v4*4;
      p [(e+0)%3] = fmaf(wf[(e+0)/3], f.x, p [(e+0)%3]);
      qv[(e+0)%3] = fmaf(wd[(e+0)/3], f.x, qv[(e+0)%3]);
      p [(e+1)%3] = fmaf(wf[(e+1)/3], f.y, p [(e+1)%3]);
      qv[(e+1)%3] = fmaf(wd[(e+1)/3], f.y, qv[(e+1)%3]);
      p [(e+2)%3] = fmaf(wf[(e+2)/3], f.z, p [(e+2)%3]);
      qv[(e+2)%3] = fmaf(wd[(e+2)/3], f.z, qv[(e+2)%3]);
      p [(e+3)%3] = fmaf(wf[(e+3)/3], f.w, p [(e+3)%3]);
      qv[(e+3)%3] = fmaf(wd[(e+3)/3], f.w, qv[(e+3)%3]);
    }
    float nrm = sqrtf(p[0]*p[0] + p[1]*p[1] + p[2]*p[2]);
    float dsq = qv[0]*qv[0] + qv[1]*qv[1] + qv[2]*qv[2];
    size_t base = ((size_t)b*N_ + m0 + m)*64 + c;
    h4 vp; vp.x = (f16)p[0];  vp.y = (f16)p[1];  vp.z = (f16)p[2];  vp.w = (f16)nrm;
    h4 vd; vd.x = (f16)qv[0]; vd.y = (f16)qv[1]; vd.z = (f16)qv[2]; vd.w = (f16)dsq;
    P0h[base] = vp;
    D0h[base] = vd;
  }
}

// ---------------- K3a: neighbor occurrence counts ----------------
__global__ __launch_bounds__(256) void count_kernel(const int* __restrict__ idxin, int* __restrict__ cnt){
  int i = blockIdx.x*256 + threadIdx.x;
  if (i < B_*N_*KNb){
    int b = i / (N_*KNb);
    atomicAdd(&cnt[b*N_ + (idxin[i] & 2047)], 1);
  }
}

// ---------------- K3b: per-channel weighted sum / sumsq of norms ----------------
__global__ __launch_bounds__(256) void stats_kernel(const h4* __restrict__ P0h,
                                                    const int* __restrict__ cnt,
                                                    float* __restrict__ gs){
  const int b = blockIdx.x >> 3;
  const int chunk = blockIdx.x & 7;
  const int w = threadIdx.x >> 6, c = threadIdx.x & 63;
  float s = 0.f, s2 = 0.f;
  const int mbase = chunk*256 + w*64;
  for (int i = 0; i < 64; ++i){
    int m = mbase + i;
    float wt = (float)cnt[b*N_ + m];
    float nv = (float)P0h[((size_t)b*N_ + m)*64 + c].w;
    s  = fmaf(wt, nv, s);
    s2 = fmaf(wt*nv, nv, s2);
  }
  __shared__ float red[8][64];
  red[w][c] = s; red[4+w][c] = s2;
  __syncthreads();
  if (w == 0) atomicAdd(&gs[c],    red[0][c]+red[1][c]+red[2][c]+red[3][c]);
  if (w == 1) atomicAdd(&gs[64+c], red[4][c]+red[5][c]+red[6][c]+red[7][c]);
}

// ---------------- K4: gather + BN + nonlinearity + mean over K ----------------
__global__ __launch_bounds__(512) void out_kernel(const h4* __restrict__ P0h, const h4* __restrict__ D0h,
                                                  const int* __restrict__ idxin, const float* __restrict__ gs,
                                                  const float* __restrict__ gamma, const float* __restrict__ beta,
                                                  float* __restrict__ outp){
  __shared__ float res[64 * 193];                  // 49,408 B
  const int b  = blockIdx.x;
  const int n0 = blockIdx.y * 64;
  const int t = threadIdx.x, w = t >> 6, c = t & 63;
  const float Ninv = 1.f / (float)(B_*N_*KNb);
  float mean = gs[c] * Ninv;
  float var  = gs[64+c] * Ninv - mean*mean;
  float istd = rsqrtf(var + 1e-5f);
  float sa = istd * gamma[c];
  float be = beta[c];
  const float kinv = 1.f/11.f;
  for (int i = 0; i < 8; ++i){
    int n = n0 + w*8 + i;
    const int* ip = idxin + ((size_t)b*N_ + n)*KNb;
    float a0=0, a1=0, a2=0;
    #pragma unroll
    for (int k = 0; k < KNb; ++k){
      int m = ip[k] & 2047;
      size_t base = ((size_t)b*N_ + m)*64 + c;
      h4 P  = P0h[base];
      h4 Dv = D0h[base];
      float pw = (float)P.w;
      float nb = (pw - mean)*sa + be;
      float sc = nb / pw;
      float p0 = (float)P.x*sc, p1 = (float)P.y*sc, p2 = (float)P.z*sc;
      float d0 = (float)Dv.x, d1 = (float)Dv.y, d2 = (float)Dv.z;
      float dot = p0*d0 + p1*d1 + p2*d2;
      float f = (dot >= 0.f) ? 0.f : dot / ((float)Dv.w + 1e-6f);
      a0 += p0 - f*d0; a1 += p1 - f*d1; a2 += p2 - f*d2;
    }
    int row = w*8 + i;
    res[row*193 + 3*c + 0] = a0*kinv;
    res[row*193 + 3*c + 1] = a1*kinv;
    res[row*193 + 3*c + 2] = a2*kinv;
  }
  __syncthreads();
  #pragma unroll
  for (int j = 0; j < 6; ++j){
    int p = t + 512*j;
    int cdim = p >> 4, nq = p & 15;
    float4 v = { res[(nq*4 + 0)*193 + cdim], res[(nq*4 + 1)*193 + cdim],
                 res[(nq*4 + 2)*193 + cdim], res[(nq*4 + 3)*193 + cdim] };
    *(float4*)(outp + ((size_t)b*192 + cdim)*N_ + n0 + nq*4) = v;
  }
}

extern "C" void kernel_launch(void* const* d_in, const int* in_sizes, int n_in,
                              void* d_out, int out_size, void* d_ws, size_t ws_size,
                              hipStream_t stream){
  const float* x     = (const float*)d_in[0];
  const float* Wf    = (const float*)d_in[1];
  const float* Wd    = (const float*)d_in[2];
  const float* gamma = (const float*)d_in[3];
  const float* beta  = (const float*)d_in[4];
  float* outp = (float*)d_out;

  // ws >= 30,408,704 B proven in R6.
  char* ws = (char*)d_ws;
  int*    idx  = (int*)   (ws);                 // 720,896
  int*    cnt  = (int*)   (ws + 720896);        // 65,536
  float*  gs   = (float*) (ws + 786432);        // 512
  h4*     P0h  = (h4*)    (ws + 1048576);       // 8,388,608
  h4*     D0h  = (h4*)    (ws + 9437184);       // 8,388,608 (ends 17,825,792)
  short*  Xs   = (short*) (ws + 1048576);       //   alias, consumed pre-project
  double* xxd  = (double*)(ws + 13631488);      //   alias
  u16*    cand = (u16*)   (ws + 13762560);      //   alias
  float*  xT   = (float*) (ws + 17825792);      // 12,582,912 (ends 30,408,704)

  hipMemsetAsync(cnt, 0, 66048, stream);        // zero cnt + gs (contiguous)
  split_kernel  <<<dim3(32, 8),  256, 0, stream>>>(x, Xs, xT, xxd);
  knn_kernel    <<<dim3(8, 64),  512, 0, stream>>>(Xs, xxd, cand);
  refine_kernel <<<4096,         256, 0, stream>>>(xT, cand, xxd, idx);
  project_kernel<<<dim3(8, 32),  256, 0, stream>>>(xT, Wf, Wd, P0h, D0h);
  count_kernel  <<<704,          256, 0, stream>>>(idx, cnt);
  stats_kernel  <<<64,           256, 0, stream>>>(P0h, cnt, gs);
  out_kernel    <<<dim3(8, 32),  512, 0, stream>>>(P0h, D0h, idx, gs, gamma, beta, outp);
}